// Round 8
// baseline (1166.119 us; speedup 1.0000x reference)
//
#include <hip/hip_runtime.h>
#include <hip/hip_bf16.h>
#include <math.h>

#define TOKENS 65536
#define C_DIM 384
#define SIXC 2304
#define SEQ 32

typedef __attribute__((ext_vector_type(8))) short short8;
typedef __attribute__((ext_vector_type(4))) float f32x4;
typedef __attribute__((address_space(3))) unsigned char lds_byte;
typedef __attribute__((address_space(1))) const unsigned char glb_byte;

__device__ __forceinline__ float bf2f(unsigned short u) {
    return __uint_as_float(((unsigned int)u) << 16);
}
__device__ __forceinline__ unsigned short f2bf(float f) {
    unsigned int u = __float_as_uint(f);
    u += 0x7fffu + ((u >> 16) & 1u);   // round-to-nearest-even
    return (unsigned short)(u >> 16);
}

// ---------------- AdaLN parameter generation (all f32) ----------------
__global__ __launch_bounds__(256) void ada_kernel(
    const float* __restrict__ xn, const float* __restrict__ aw,
    const float* __restrict__ ab, float* __restrict__ params)
{
    __shared__ float sx[256];
    int b = blockIdx.y;
    int n = blockIdx.x * 256 + threadIdx.x;
    float xv = xn[b * 256 + threadIdx.x];
    sx[threadIdx.x] = xv / (1.0f + __expf(-xv));
    __syncthreads();
    float acc = ab[n];
    for (int k = 0; k < 256; ++k)
        acc += sx[k] * aw[(size_t)k * SIXC + n];
    params[b * SIXC + n] = acc;
}

// ---------------- weight transpose + bf16 convert ----------------
// W[K][N] f32  ->  WT[N][K] bf16.
__global__ __launch_bounds__(256) void transpose_w_kernel(
    const float* __restrict__ W, unsigned short* __restrict__ WT, int K, int N)
{
    __shared__ float t[32][33];
    int kb = blockIdx.x * 32, nb = blockIdx.y * 32;
    int tn = threadIdx.x & 31, t8 = threadIdx.x >> 5;
#pragma unroll
    for (int i = 0; i < 4; ++i) {
        int k = t8 + i * 8;
        t[k][tn] = W[(size_t)(kb + k) * N + nb + tn];
    }
    __syncthreads();
#pragma unroll
    for (int i = 0; i < 4; ++i) {
        int n = t8 + i * 8;
        WT[(size_t)(nb + n) * K + kb + tn] = f2bf(t[tn][n]);
    }
}

// ---------------- LayerNorm + modulate ----------------
template<int IN_F32>
__global__ __launch_bounds__(256) void ln_mod_kernel(
    const void* __restrict__ inp, unsigned short* __restrict__ out,
    const float* __restrict__ params, int shift_off, int scale_off)
{
    int t = blockIdx.x * 4 + (threadIdx.x >> 6);
    int lane = threadIdx.x & 63;
    float v[6];
    float s = 0.f, s2 = 0.f;
    if (IN_F32) {
        const float* px = (const float*)inp + (size_t)t * C_DIM;
#pragma unroll
        for (int j = 0; j < 6; ++j) { v[j] = px[lane + (j << 6)]; s += v[j]; s2 += v[j] * v[j]; }
    } else {
        const unsigned short* px = (const unsigned short*)inp + (size_t)t * C_DIM;
#pragma unroll
        for (int j = 0; j < 6; ++j) { v[j] = bf2f(px[lane + (j << 6)]); s += v[j]; s2 += v[j] * v[j]; }
    }
#pragma unroll
    for (int m = 32; m >= 1; m >>= 1) {
        s += __shfl_xor(s, m, 64);
        s2 += __shfl_xor(s2, m, 64);
    }
    float mean = s * (1.0f / 384.0f);
    float var = s2 * (1.0f / 384.0f) - mean * mean;
    float rs = rsqrtf(var + 1e-5f);
    int b = t >> 15;
    const float* shp = params + b * SIXC + shift_off;
    const float* scp = params + b * SIXC + scale_off;
    unsigned short* po = out + (size_t)t * C_DIM;
#pragma unroll
    for (int j = 0; j < 6; ++j) {
        int c = lane + (j << 6);
        po[c] = f2bf((v[j] - mean) * rs * (1.0f + scp[c]) + shp[c]);
    }
}

// ---------------- GEMM v3: 128x384 tile, global_load_lds staging --------
// A[M][K] bf16, WT[N][K] bf16 (pre-transposed), bias f32.
// EPI: 0 = store, 1 = exact GELU, 2 = res + gate*val, 3 = qkv 18-plane layout
// RESF32 / OUTF32: dtypes of residual / output.
template<int EPI, int RESF32, int OUTF32>
__global__ __launch_bounds__(512) void gemm_kernel(
    const unsigned short* __restrict__ Ab,
    const unsigned short* __restrict__ WT, const float* __restrict__ bias,
    void* __restrict__ outp, int M, int N, int K,
    const void* __restrict__ res, const float* __restrict__ params,
    int gate_off)
{
    __shared__ __align__(16) unsigned short As[128 * 32];   // 8 KB, linear
    __shared__ __align__(16) unsigned short Bs[384 * 32];   // 24 KB, linear
    int tid = threadIdx.x;
    int lane = tid & 63;
    int wave = tid >> 6;          // 0..7
    int wm = wave >> 2;           // 0..1  (64-row strip)
    int wn = wave & 3;            // 0..3  (96-col strip)
    int bn0 = blockIdx.x * 384;
    int bm0 = blockIdx.y * 128;

    f32x4 acc[4][6] = {};

    // per-lane source offsets for global_load_lds (dest = base + lane*16B)
    int srow = lane >> 2;               // 0..15
    int skc = (lane & 3) << 3;          // element offset 0/8/16/24
    int nk = K >> 5;
    for (int kt = 0; kt < nk; ++kt) {
        int k0 = kt << 5;
        // A: 128x32 = 8 wave-regions of 16 rows
        {
            const unsigned short* gp = Ab + (size_t)(bm0 + wave * 16 + srow) * K + k0 + skc;
            __builtin_amdgcn_global_load_lds((glb_byte*)gp, (lds_byte*)&As[wave * 16 * 32], 16, 0, 0);
        }
        // B: 384x32 = 24 wave-regions, 3 per wave
#pragma unroll
        for (int j = 0; j < 3; ++j) {
            int r0 = (wave * 3 + j) << 4;
            const unsigned short* gp = WT + (size_t)(bn0 + r0 + srow) * K + k0 + skc;
            __builtin_amdgcn_global_load_lds((glb_byte*)gp, (lds_byte*)&Bs[r0 * 32], 16, 0, 0);
        }
        __syncthreads();
        int kg = (lane >> 4) << 3;
        int lr = lane & 15;
        short8 af[4], bf[6];
#pragma unroll
        for (int mi = 0; mi < 4; ++mi)
            af[mi] = *(const short8*)&As[(wm * 64 + mi * 16 + lr) * 32 + kg];
#pragma unroll
        for (int ni = 0; ni < 6; ++ni)
            bf[ni] = *(const short8*)&Bs[(wn * 96 + ni * 16 + lr) * 32 + kg];
#pragma unroll
        for (int ni = 0; ni < 6; ++ni)
#pragma unroll
            for (int mi = 0; mi < 4; ++mi)
                acc[mi][ni] = __builtin_amdgcn_mfma_f32_16x16x32_bf16(af[mi], bf[ni], acc[mi][ni], 0, 0, 0);
        __syncthreads();
    }

    int lc = lane & 15;
    int lrow = (lane >> 4) << 2;
#pragma unroll
    for (int mi = 0; mi < 4; ++mi) {
#pragma unroll
        for (int ni = 0; ni < 6; ++ni) {
            int col = bn0 + wn * 96 + ni * 16 + lc;
            float bv = bias[col];
#pragma unroll
            for (int r = 0; r < 4; ++r) {
                int row = bm0 + wm * 64 + mi * 16 + lrow + r;
                float v = acc[mi][ni][r] + bv;
                if (EPI == 1) {
                    v = 0.5f * v * (1.0f + erff(v * 0.70710678118f));
                } else if (EPI == 2) {
                    size_t oofs = (size_t)row * N + col;
                    int b = row >> 15;
                    float rv = RESF32 ? ((const float*)res)[oofs]
                                      : bf2f(((const unsigned short*)res)[oofs]);
                    v = rv + params[b * SIXC + gate_off + col] * v;
                }
                if (EPI == 3) {
                    // qkv plane layout: [p*6+head][token][64]
                    int p = col / 384;
                    int head = (col - p * 384) >> 6;
                    int hd = col & 63;
                    size_t oofs = ((size_t)(p * 6 + head) << 22) + ((size_t)row << 6) + hd;
                    ((unsigned short*)outp)[oofs] = f2bf(v);
                } else {
                    size_t oofs = (size_t)row * N + col;
                    if (OUTF32) ((float*)outp)[oofs] = v;
                    else        ((unsigned short*)outp)[oofs] = f2bf(v);
                }
            }
        }
    }
}

// ---------------- axial attention (S=32, hd=64), plane-layout qkv -------
__global__ __launch_bounds__(256) void attn_kernel(
    const unsigned short* __restrict__ qkv, unsigned short* __restrict__ attn_out,
    int stride, int first)
{
    __shared__ float qs[32][66], ks[32][66], vs[32][66];
    __shared__ float ss[32][33];
    int g = blockIdx.x, head = blockIdx.y;
    int o = g / stride, i0 = g - o * stride;
    int base = o * (SEQ * stride) + i0;
    int tid = threadIdx.x;
    int row = tid >> 3, gq = tid & 7;
    int tok = base + row * stride;
    size_t tofs = ((size_t)tok << 6) + gq * 8;
    {
        uint4 vq = *(const uint4*)(qkv + (((size_t)head) << 22) + tofs);
        uint4 vk = *(const uint4*)(qkv + (((size_t)(6 + head)) << 22) + tofs);
        uint4 vv = *(const uint4*)(qkv + (((size_t)(12 + head)) << 22) + tofs);
        const unsigned short* pq = (const unsigned short*)&vq;
        const unsigned short* pk = (const unsigned short*)&vk;
        const unsigned short* pv = (const unsigned short*)&vv;
#pragma unroll
        for (int j = 0; j < 8; ++j) {
            qs[row][gq * 8 + j] = bf2f(pq[j]);
            ks[row][gq * 8 + j] = bf2f(pk[j]);
            vs[row][gq * 8 + j] = bf2f(pv[j]);
        }
    }
    __syncthreads();

    float sj[4];
#pragma unroll
    for (int jj = 0; jj < 4; ++jj) {
        int j = gq + jj * 8;
        float s = 0.f;
        for (int c = 0; c < 64; ++c) s += qs[row][c] * ks[j][c];
        sj[jj] = s * 0.125f;
    }
    float mx = fmaxf(fmaxf(sj[0], sj[1]), fmaxf(sj[2], sj[3]));
#pragma unroll
    for (int m = 1; m < 8; m <<= 1) mx = fmaxf(mx, __shfl_xor(mx, m, 8));
    float sum = 0.f;
#pragma unroll
    for (int jj = 0; jj < 4; ++jj) {
        float e = __expf(sj[jj] - mx);
        ss[row][gq + jj * 8] = e;
        sum += e;
    }
#pragma unroll
    for (int m = 1; m < 8; m <<= 1) sum += __shfl_xor(sum, m, 8);
    float inv = 1.0f / sum;
    __syncthreads();

    float ov[8] = {0.f, 0.f, 0.f, 0.f, 0.f, 0.f, 0.f, 0.f};
    for (int j = 0; j < 32; ++j) {
        float p = ss[row][j];
#pragma unroll
        for (int c8 = 0; c8 < 8; ++c8) ov[c8] += p * vs[j][gq * 8 + c8];
    }
    unsigned short* dst = attn_out + (size_t)tok * C_DIM + head * 64 + gq * 8;
    if (first) {
#pragma unroll
        for (int c8 = 0; c8 < 8; ++c8) dst[c8] = f2bf(ov[c8] * inv);
    } else {
#pragma unroll
        for (int c8 = 0; c8 < 8; ++c8) dst[c8] = f2bf(bf2f(dst[c8]) + ov[c8] * inv);
    }
}

extern "C" void kernel_launch(void* const* d_in, const int* in_sizes, int n_in,
                              void* d_out, int out_size, void* d_ws, size_t ws_size,
                              hipStream_t stream) {
    const float* x      = (const float*)d_in[0];
    const float* xnoise = (const float*)d_in[1];
    const float* ada_w  = (const float*)d_in[2];
    const float* ada_b  = (const float*)d_in[3];
    const float* qkv_w  = (const float*)d_in[4];
    const float* qkv_b  = (const float*)d_in[5];
    const float* out_w  = (const float*)d_in[6];
    const float* out_b  = (const float*)d_in[7];
    const float* mlp_w1 = (const float*)d_in[8];
    const float* mlp_b1 = (const float*)d_in[9];
    const float* mlp_w2 = (const float*)d_in[10];
    const float* mlp_b2 = (const float*)d_in[11];

    // ws layout (244MB):
    //   params 32KB | WT 4MB | A 48MB (norm_x -> attn_out -> X1 bf16) | B 192MB (qkv planes -> gelu acts)
    // d_out doubles as bf16 h_in scratch between ln2 and mlp2.
    char* ws = (char*)d_ws;
    float* params = (float*)ws;
    unsigned short* wt_qkv = (unsigned short*)(ws + 32768);
    unsigned short* wt_out = wt_qkv + 442368;     // 384*1152
    unsigned short* wt_m1  = wt_out + 147456;     // 384*384
    unsigned short* wt_m2  = wt_m1 + 589824;      // 384*1536
    unsigned short* Areg = (unsigned short*)(ws + 32768 + 4194304UL);
    unsigned short* Breg = Areg + 25165824UL;     // +48MB
    unsigned short* hin  = (unsigned short*)d_out;

    ada_kernel<<<dim3(9, 2), 256, 0, stream>>>(xnoise, ada_w, ada_b, params);
    transpose_w_kernel<<<dim3(12, 36), 256, 0, stream>>>(qkv_w, wt_qkv, 384, 1152);
    transpose_w_kernel<<<dim3(12, 12), 256, 0, stream>>>(out_w, wt_out, 384, 384);
    transpose_w_kernel<<<dim3(12, 48), 256, 0, stream>>>(mlp_w1, wt_m1, 384, 1536);
    transpose_w_kernel<<<dim3(48, 12), 256, 0, stream>>>(mlp_w2, wt_m2, 1536, 384);

    // LN1 + modulate:  x(f32) -> A (norm_x bf16)
    ln_mod_kernel<1><<<16384, 256, 0, stream>>>(x, Areg, params, 0, 384);
    // qkv: A @ qkv_w -> B, 18-plane layout [p*6+h][tok][64]
    gemm_kernel<3, 0, 0><<<dim3(3, 512), 512, 0, stream>>>(Areg, wt_qkv, qkv_b, Breg,
                                                           TOKENS, 1152, 384, nullptr, nullptr, 0);
    // 3 axial attentions, accumulate bf16 into A (norm_x dead)
    attn_kernel<<<dim3(2048, 6), 256, 0, stream>>>(Breg, Areg, 1, 1);
    attn_kernel<<<dim3(2048, 6), 256, 0, stream>>>(Breg, Areg, 32, 0);
    attn_kernel<<<dim3(2048, 6), 256, 0, stream>>>(Breg, Areg, 1024, 0);
    // out-proj + gate1 + residual(x f32) -> X1 bf16, in-place over Areg (grid.x=1: block-local rows)
    gemm_kernel<2, 1, 0><<<dim3(1, 512), 512, 0, stream>>>(Areg, wt_out, out_b, Areg,
                                                           TOKENS, 384, 384, x, params, 768);
    // LN2 + modulate:  A (X1 bf16) -> h_in bf16 (staged in d_out)
    ln_mod_kernel<0><<<16384, 256, 0, stream>>>(Areg, hin, params, 1152, 1536);
    // mlp1 + gelu:  h_in @ mlp_w1 -> B (192MB bf16)
    gemm_kernel<1, 0, 0><<<dim3(4, 512), 512, 0, stream>>>(hin, wt_m1, mlp_b1, Breg,
                                                           TOKENS, 1536, 384, nullptr, nullptr, 0);
    // mlp2 + gate2 + residual(X1 bf16 in Areg) -> d_out (f32 final)
    gemm_kernel<2, 0, 1><<<dim3(1, 512), 512, 0, stream>>>(Breg, wt_m2, mlp_b2, d_out,
                                                           TOKENS, 384, 1536, Areg, params, 1920);
}

// Round 9
// 1105.762 us; speedup vs baseline: 1.0546x; 1.0546x over previous
//
#include <hip/hip_runtime.h>
#include <hip/hip_bf16.h>
#include <math.h>

#define TOKENS 65536
#define C_DIM 384
#define SIXC 2304
#define SEQ 32

typedef __attribute__((ext_vector_type(8))) short short8;
typedef __attribute__((ext_vector_type(4))) float f32x4;
typedef __attribute__((address_space(3))) unsigned char lds_byte;
typedef __attribute__((address_space(1))) const unsigned char glb_byte;

__device__ __forceinline__ float bf2f(unsigned short u) {
    return __uint_as_float(((unsigned int)u) << 16);
}
__device__ __forceinline__ unsigned short f2bf(float f) {
    unsigned int u = __float_as_uint(f);
    u += 0x7fffu + ((u >> 16) & 1u);   // round-to-nearest-even
    return (unsigned short)(u >> 16);
}

// ---------------- AdaLN parameter generation (all f32) ----------------
__global__ __launch_bounds__(256) void ada_kernel(
    const float* __restrict__ xn, const float* __restrict__ aw,
    const float* __restrict__ ab, float* __restrict__ params)
{
    __shared__ float sx[256];
    int b = blockIdx.y;
    int n = blockIdx.x * 256 + threadIdx.x;
    float xv = xn[b * 256 + threadIdx.x];
    sx[threadIdx.x] = xv / (1.0f + __expf(-xv));
    __syncthreads();
    float acc = ab[n];
    for (int k = 0; k < 256; ++k)
        acc += sx[k] * aw[(size_t)k * SIXC + n];
    params[b * SIXC + n] = acc;
}

// ---------------- weight transpose + bf16 convert ----------------
// W[K][N] f32  ->  WT[N][K] bf16.
__global__ __launch_bounds__(256) void transpose_w_kernel(
    const float* __restrict__ W, unsigned short* __restrict__ WT, int K, int N)
{
    __shared__ float t[32][33];
    int kb = blockIdx.x * 32, nb = blockIdx.y * 32;
    int tn = threadIdx.x & 31, t8 = threadIdx.x >> 5;
#pragma unroll
    for (int i = 0; i < 4; ++i) {
        int k = t8 + i * 8;
        t[k][tn] = W[(size_t)(kb + k) * N + nb + tn];
    }
    __syncthreads();
#pragma unroll
    for (int i = 0; i < 4; ++i) {
        int n = t8 + i * 8;
        WT[(size_t)(nb + n) * K + kb + tn] = f2bf(t[tn][n]);
    }
}

// ---------------- LayerNorm + modulate ----------------
template<int IN_F32>
__global__ __launch_bounds__(256) void ln_mod_kernel(
    const void* __restrict__ inp, unsigned short* __restrict__ out,
    const float* __restrict__ params, int shift_off, int scale_off)
{
    int t = blockIdx.x * 4 + (threadIdx.x >> 6);
    int lane = threadIdx.x & 63;
    float v[6];
    float s = 0.f, s2 = 0.f;
    if (IN_F32) {
        const float* px = (const float*)inp + (size_t)t * C_DIM;
#pragma unroll
        for (int j = 0; j < 6; ++j) { v[j] = px[lane + (j << 6)]; s += v[j]; s2 += v[j] * v[j]; }
    } else {
        const unsigned short* px = (const unsigned short*)inp + (size_t)t * C_DIM;
#pragma unroll
        for (int j = 0; j < 6; ++j) { v[j] = bf2f(px[lane + (j << 6)]); s += v[j]; s2 += v[j] * v[j]; }
    }
#pragma unroll
    for (int m = 32; m >= 1; m >>= 1) {
        s += __shfl_xor(s, m, 64);
        s2 += __shfl_xor(s2, m, 64);
    }
    float mean = s * (1.0f / 384.0f);
    float var = s2 * (1.0f / 384.0f) - mean * mean;
    float rs = rsqrtf(var + 1e-5f);
    int b = t >> 15;
    const float* shp = params + b * SIXC + shift_off;
    const float* scp = params + b * SIXC + scale_off;
    unsigned short* po = out + (size_t)t * C_DIM;
#pragma unroll
    for (int j = 0; j < 6; ++j) {
        int c = lane + (j << 6);
        po[c] = f2bf((v[j] - mean) * rs * (1.0f + scp[c]) + shp[c]);
    }
}

// ---------------- GEMM v4: m97 structure ------------------------------
// 128x128 tile, 256 threads / 4 waves (2x2), BK=32, acc 4x4,
// global_load_lds(16B) staging into linear LDS.
// A[M][K] bf16, WT[N][K] bf16, bias f32.
// EPI: 0 = store, 1 = exact GELU, 2 = res + gate*val, 3 = qkv plane layout
template<int EPI, int RESF32, int OUTF32>
__global__ __launch_bounds__(256) void gemm_kernel(
    const unsigned short* __restrict__ Ab,
    const unsigned short* __restrict__ WT, const float* __restrict__ bias,
    void* __restrict__ outp, int M, int N, int K,
    const void* __restrict__ res, const float* __restrict__ params,
    int gate_off)
{
    __shared__ __align__(16) unsigned short As[128 * 32];   // 8 KB linear
    __shared__ __align__(16) unsigned short Bs[128 * 32];   // 8 KB linear
    int tid = threadIdx.x;
    int lane = tid & 63;
    int wave = tid >> 6;          // 0..3
    int wm = wave >> 1;           // 0..1 (64-row strip)
    int wn = wave & 1;            // 0..1 (64-col strip)
    int bn0 = blockIdx.x * 128;
    int bm0 = blockIdx.y * 128;

    f32x4 acc[4][4] = {};

    // per-lane source offsets (dest = base + lane*16B)
    int srow = lane >> 2;               // 0..15
    int skc = (lane & 3) << 3;          // 0/8/16/24
    int nk = K >> 5;
    for (int kt = 0; kt < nk; ++kt) {
        int k0 = kt << 5;
        // A: 128x32 -> 8 regions of 16 rows; wave handles 2
        {
            const unsigned short* gp = Ab + (size_t)(bm0 + wave * 32 + srow) * K + k0 + skc;
            __builtin_amdgcn_global_load_lds((glb_byte*)gp, (lds_byte*)&As[(wave * 32) * 32], 16, 0, 0);
            const unsigned short* gp2 = Ab + (size_t)(bm0 + wave * 32 + 16 + srow) * K + k0 + skc;
            __builtin_amdgcn_global_load_lds((glb_byte*)gp2, (lds_byte*)&As[(wave * 32 + 16) * 32], 16, 0, 0);
        }
        // B: 128x32 likewise
        {
            const unsigned short* gp = WT + (size_t)(bn0 + wave * 32 + srow) * K + k0 + skc;
            __builtin_amdgcn_global_load_lds((glb_byte*)gp, (lds_byte*)&Bs[(wave * 32) * 32], 16, 0, 0);
            const unsigned short* gp2 = WT + (size_t)(bn0 + wave * 32 + 16 + srow) * K + k0 + skc;
            __builtin_amdgcn_global_load_lds((glb_byte*)gp2, (lds_byte*)&Bs[(wave * 32 + 16) * 32], 16, 0, 0);
        }
        __syncthreads();
        int kg = (lane >> 4) << 3;
        int lr = lane & 15;
        short8 af[4], bf[4];
#pragma unroll
        for (int mi = 0; mi < 4; ++mi)
            af[mi] = *(const short8*)&As[(wm * 64 + mi * 16 + lr) * 32 + kg];
#pragma unroll
        for (int ni = 0; ni < 4; ++ni)
            bf[ni] = *(const short8*)&Bs[(wn * 64 + ni * 16 + lr) * 32 + kg];
#pragma unroll
        for (int ni = 0; ni < 4; ++ni)
#pragma unroll
            for (int mi = 0; mi < 4; ++mi)
                acc[mi][ni] = __builtin_amdgcn_mfma_f32_16x16x32_bf16(af[mi], bf[ni], acc[mi][ni], 0, 0, 0);
        __syncthreads();
    }

    int lc = lane & 15;
    int lrow = (lane >> 4) << 2;
#pragma unroll
    for (int mi = 0; mi < 4; ++mi) {
#pragma unroll
        for (int ni = 0; ni < 4; ++ni) {
            int col = bn0 + wn * 64 + ni * 16 + lc;
            float bv = bias[col];
#pragma unroll
            for (int r = 0; r < 4; ++r) {
                int row = bm0 + wm * 64 + mi * 16 + lrow + r;
                float v = acc[mi][ni][r] + bv;
                if (EPI == 1) {
                    v = 0.5f * v * (1.0f + erff(v * 0.70710678118f));
                } else if (EPI == 2) {
                    size_t oofs = (size_t)row * N + col;
                    int b = row >> 15;
                    float rv = RESF32 ? ((const float*)res)[oofs]
                                      : bf2f(((const unsigned short*)res)[oofs]);
                    v = rv + params[b * SIXC + gate_off + col] * v;
                }
                if (EPI == 3) {
                    // qkv plane layout: [p*6+head][token][64]
                    int p = col / 384;
                    int head = (col - p * 384) >> 6;
                    int hd = col & 63;
                    size_t oofs = ((size_t)(p * 6 + head) << 22) + ((size_t)row << 6) + hd;
                    ((unsigned short*)outp)[oofs] = f2bf(v);
                } else {
                    size_t oofs = (size_t)row * N + col;
                    if (OUTF32) ((float*)outp)[oofs] = v;
                    else        ((unsigned short*)outp)[oofs] = f2bf(v);
                }
            }
        }
    }
}

// ---------------- axial attention (S=32, hd=64), plane-layout qkv -------
__global__ __launch_bounds__(256) void attn_kernel(
    const unsigned short* __restrict__ qkv, unsigned short* __restrict__ attn_out,
    int stride, int first)
{
    __shared__ float qs[32][66], ks[32][66], vs[32][66];
    __shared__ float ss[32][33];
    int g = blockIdx.x, head = blockIdx.y;
    int o = g / stride, i0 = g - o * stride;
    int base = o * (SEQ * stride) + i0;
    int tid = threadIdx.x;
    int row = tid >> 3, gq = tid & 7;
    int tok = base + row * stride;
    size_t tofs = ((size_t)tok << 6) + gq * 8;
    {
        uint4 vq = *(const uint4*)(qkv + (((size_t)head) << 22) + tofs);
        uint4 vk = *(const uint4*)(qkv + (((size_t)(6 + head)) << 22) + tofs);
        uint4 vv = *(const uint4*)(qkv + (((size_t)(12 + head)) << 22) + tofs);
        const unsigned short* pq = (const unsigned short*)&vq;
        const unsigned short* pk = (const unsigned short*)&vk;
        const unsigned short* pv = (const unsigned short*)&vv;
#pragma unroll
        for (int j = 0; j < 8; ++j) {
            qs[row][gq * 8 + j] = bf2f(pq[j]);
            ks[row][gq * 8 + j] = bf2f(pk[j]);
            vs[row][gq * 8 + j] = bf2f(pv[j]);
        }
    }
    __syncthreads();

    float sj[4];
#pragma unroll
    for (int jj = 0; jj < 4; ++jj) {
        int j = gq + jj * 8;
        float s = 0.f;
        for (int c = 0; c < 64; ++c) s += qs[row][c] * ks[j][c];
        sj[jj] = s * 0.125f;
    }
    float mx = fmaxf(fmaxf(sj[0], sj[1]), fmaxf(sj[2], sj[3]));
#pragma unroll
    for (int m = 1; m < 8; m <<= 1) mx = fmaxf(mx, __shfl_xor(mx, m, 8));
    float sum = 0.f;
#pragma unroll
    for (int jj = 0; jj < 4; ++jj) {
        float e = __expf(sj[jj] - mx);
        ss[row][gq + jj * 8] = e;
        sum += e;
    }
#pragma unroll
    for (int m = 1; m < 8; m <<= 1) sum += __shfl_xor(sum, m, 8);
    float inv = 1.0f / sum;
    __syncthreads();

    float ov[8] = {0.f, 0.f, 0.f, 0.f, 0.f, 0.f, 0.f, 0.f};
    for (int j = 0; j < 32; ++j) {
        float p = ss[row][j];
#pragma unroll
        for (int c8 = 0; c8 < 8; ++c8) ov[c8] += p * vs[j][gq * 8 + c8];
    }
    unsigned short* dst = attn_out + (size_t)tok * C_DIM + head * 64 + gq * 8;
    if (first) {
#pragma unroll
        for (int c8 = 0; c8 < 8; ++c8) dst[c8] = f2bf(ov[c8] * inv);
    } else {
#pragma unroll
        for (int c8 = 0; c8 < 8; ++c8) dst[c8] = f2bf(bf2f(dst[c8]) + ov[c8] * inv);
    }
}

extern "C" void kernel_launch(void* const* d_in, const int* in_sizes, int n_in,
                              void* d_out, int out_size, void* d_ws, size_t ws_size,
                              hipStream_t stream) {
    const float* x      = (const float*)d_in[0];
    const float* xnoise = (const float*)d_in[1];
    const float* ada_w  = (const float*)d_in[2];
    const float* ada_b  = (const float*)d_in[3];
    const float* qkv_w  = (const float*)d_in[4];
    const float* qkv_b  = (const float*)d_in[5];
    const float* out_w  = (const float*)d_in[6];
    const float* out_b  = (const float*)d_in[7];
    const float* mlp_w1 = (const float*)d_in[8];
    const float* mlp_b1 = (const float*)d_in[9];
    const float* mlp_w2 = (const float*)d_in[10];
    const float* mlp_b2 = (const float*)d_in[11];

    // ws layout (244MB):
    //   params 32KB | WT 4MB | A 48MB bf16 (norm_x -> attn_out -> h_in) | B 192MB bf16 (qkv planes -> gelu acts)
    // X1 lives as f32 in d_out (written by out-proj, read by ln2 + mlp2-residual RMW).
    char* ws = (char*)d_ws;
    float* params = (float*)ws;
    unsigned short* wt_qkv = (unsigned short*)(ws + 32768);
    unsigned short* wt_out = wt_qkv + 442368;     // 384*1152
    unsigned short* wt_m1  = wt_out + 147456;     // 384*384
    unsigned short* wt_m2  = wt_m1 + 589824;      // 384*1536
    unsigned short* Areg = (unsigned short*)(ws + 32768 + 4194304UL);
    unsigned short* Breg = Areg + 25165824UL;     // +48MB

    ada_kernel<<<dim3(9, 2), 256, 0, stream>>>(xnoise, ada_w, ada_b, params);
    transpose_w_kernel<<<dim3(12, 36), 256, 0, stream>>>(qkv_w, wt_qkv, 384, 1152);
    transpose_w_kernel<<<dim3(12, 12), 256, 0, stream>>>(out_w, wt_out, 384, 384);
    transpose_w_kernel<<<dim3(12, 48), 256, 0, stream>>>(mlp_w1, wt_m1, 384, 1536);
    transpose_w_kernel<<<dim3(48, 12), 256, 0, stream>>>(mlp_w2, wt_m2, 1536, 384);

    // LN1 + modulate:  x(f32) -> A (norm_x bf16)
    ln_mod_kernel<1><<<16384, 256, 0, stream>>>(x, Areg, params, 0, 384);
    // qkv: A @ qkv_w -> B, 18-plane layout [p*6+h][tok][64]
    gemm_kernel<3, 0, 0><<<dim3(9, 512), 256, 0, stream>>>(Areg, wt_qkv, qkv_b, Breg,
                                                           TOKENS, 1152, 384, nullptr, nullptr, 0);
    // 3 axial attentions, accumulate bf16 into A (norm_x dead)
    attn_kernel<<<dim3(2048, 6), 256, 0, stream>>>(Breg, Areg, 1, 1);
    attn_kernel<<<dim3(2048, 6), 256, 0, stream>>>(Breg, Areg, 32, 0);
    attn_kernel<<<dim3(2048, 6), 256, 0, stream>>>(Breg, Areg, 1024, 0);
    // out-proj + gate1 + residual(x f32) -> d_out (X1, f32)
    gemm_kernel<2, 1, 1><<<dim3(3, 512), 256, 0, stream>>>(Areg, wt_out, out_b, d_out,
                                                           TOKENS, 384, 384, x, params, 768);
    // LN2 + modulate:  d_out(f32) -> A (h_in bf16)
    ln_mod_kernel<1><<<16384, 256, 0, stream>>>(d_out, Areg, params, 1152, 1536);
    // mlp1 + gelu:  A @ mlp_w1 -> B (192MB bf16)
    gemm_kernel<1, 0, 0><<<dim3(12, 512), 256, 0, stream>>>(Areg, wt_m1, mlp_b1, Breg,
                                                            TOKENS, 1536, 384, nullptr, nullptr, 0);
    // mlp2 + gate2 + residual(d_out f32, same-thread RMW) -> d_out (f32)
    gemm_kernel<2, 1, 1><<<dim3(3, 512), 256, 0, stream>>>(Breg, wt_m2, mlp_b2, d_out,
                                                           TOKENS, 384, 1536, d_out, params, 1920);
}